// Round 12
// baseline (209.611 us; speedup 1.0000x reference)
//
#include <hip/hip_runtime.h>
#include <hip/hip_bf16.h>
#include <stdint.h>

#define B_ 64
#define N_ 1024
#define E_ 16384
#define F_ 128
#define H_ 64
#define T_ 10
#define BN (B_*N_)   // 65536
#define BE (B_*E_)   // 1048576
#define EPAD (E_ + 12 * N_)   // 28672: per-graph compact CSR region (12 slack/node for virtual edges)

// sigmoid(z) >= p  <=>  z >= log(p/(1-p))
#define TH_INNER (-0.84729786f)   // logit(0.3)
#define TH_CROSS (-2.1972246f)    // logit(0.1)

typedef __attribute__((ext_vector_type(8))) short short8;  // bf16x8 MFMA frag
typedef __attribute__((ext_vector_type(4))) float f32x4;   // MFMA acc

__device__ __forceinline__ float ld1(const void* p, int i, int bf) {
    if (bf) {
        uint16_t u = ((const uint16_t*)p)[i];
        return __uint_as_float(((uint32_t)u) << 16);
    }
    return ((const float*)p)[i];
}

__device__ __forceinline__ short to_bf(float x) {
    return (short)__bfloat16_as_ushort(__float2bfloat16(x));
}

__device__ __forceinline__ uint32_t pack_bf2(float lo, float hi) {
    uint32_t l = (uint32_t)__bfloat16_as_ushort(__float2bfloat16(lo));
    uint32_t h = (uint32_t)__bfloat16_as_ushort(__float2bfloat16(hi));
    return l | (h << 16);
}

__device__ __forceinline__ float bflo(uint32_t u) { return __uint_as_float(u << 16); }
__device__ __forceinline__ float bfhi(uint32_t u) { return __uint_as_float(u & 0xffff0000u); }

// ---------------- fused: per-graph dense CSR build (blocks 0..63) + frag prep (blocks 64..65) ----------------
__global__ __launch_bounds__(1024) void k_bucket(const int* __restrict__ src,
                                                 const int* __restrict__ dst,
                                                 int* __restrict__ cnt,
                                                 int* __restrict__ offs,
                                                 int* __restrict__ bucket,
                                                 float* __restrict__ gsum,
                                                 uint32_t* __restrict__ y1pad,
                                                 uint32_t* __restrict__ y2pad,
                                                 const void* __restrict__ W1,
                                                 const void* __restrict__ W2,
                                                 const void* __restrict__ tokens,
                                                 int* __restrict__ flag,
                                                 short8* __restrict__ Bfr,
                                                 short8* __restrict__ Bfr2) {
    __shared__ int lcnt[N_];
    __shared__ int wsum[16], wpre[16];
    int t = threadIdx.x;
    if (blockIdx.x >= B_) {                       // ---- prep path ----
        uint32_t du = ((const uint32_t*)tokens)[t & 63];
        float dlo = __uint_as_float(du << 16);
        unsigned long long vote = __ballot(fabsf(dlo) <= 1.0f);
        int bf = (vote == ~0ull) ? 1 : 0;
        if (blockIdx.x == B_ && t == 0) *flag = bf;
        int f = (blockIdx.x - B_) * 1024 + t;     // [0, 2048)
        if (f < 1280) {                           // Bfr: [128 x 80] = W1 | tokens^T
            int c = f / 320, rem = f % 320;
            int nt = rem / 64, lane = rem % 64;
            int q = lane >> 4, n = nt * 16 + (lane & 15);
            int k0 = c * 32 + q * 8;
            short8 v;
#pragma unroll
            for (int j = 0; j < 8; ++j) {
                int k = k0 + j;
                float x = 0.f;
                if (n < H_) x = ld1(W1, k * H_ + n, bf);
                else if (n < H_ + T_) x = ld1(tokens, (n - H_) * F_ + k, bf);
                v[j] = to_bf(x);
            }
            Bfr[f] = v;
        } else if (f < 1792) {                    // Bfr2: W2 [64 x 64]
            int f2 = f - 1280;
            int c = f2 / 256, rem = f2 % 256;
            int nt = rem / 64, lane = rem % 64;
            int q = lane >> 4, n = nt * 16 + (lane & 15);
            int k0 = c * 32 + q * 8;
            short8 v;
#pragma unroll
            for (int j = 0; j < 8; ++j) v[j] = to_bf(ld1(W2, (k0 + j) * H_ + n, bf));
            Bfr2[f2] = v;
        }
        return;
    }
    // ---- bucket path (one block per graph) ----
    int g = blockIdx.x;
    lcnt[t] = 0;
    if (t < 64) gsum[g * 64 + t] = 0.f;           // zero this graph's pool row
    if (g == 0) {                                 // zero pad rows once
        if (t < 32) y1pad[t] = 0;
        else if (t < 64) y2pad[t - 32] = 0;
    }
    __syncthreads();
#pragma unroll
    for (int it = 0; it < 16; ++it) {
        int i = g * E_ + it * 1024 + t;
        int d = __builtin_nontemporal_load(&dst[i]);
        atomicAdd(&lcnt[d], 1);
    }
    __syncthreads();
    // two-level exclusive scan of lcnt
    int lane = t & 63, wvid = t >> 6;
    int v = lcnt[t];
    int incl = v;
#pragma unroll
    for (int d = 1; d < 64; d <<= 1) {
        int u = __shfl_up(incl, d);
        if (lane >= d) incl += u;
    }
    if (lane == 63) wsum[wvid] = incl;
    __syncthreads();
    if (wvid == 0) {
        int s = (lane < 16) ? wsum[lane] : 0;
#pragma unroll
        for (int d = 1; d < 16; d <<= 1) {
            int u = __shfl_up(s, d);
            if (lane >= d) s += u;
        }
        if (lane < 16) wpre[lane] = s;
    }
    __syncthreads();
    int wprefix = (wvid == 0) ? 0 : wpre[wvid - 1];
    int base = (incl - v) + wprefix + 12 * t;     // exclusive prefix + virtual-edge slack
    cnt[g * N_ + t] = v;
    offs[g * N_ + t] = g * EPAD + base;           // absolute offset into bucket
    __syncthreads();
    lcnt[t] = base;                               // reuse as within-graph cursor
    __syncthreads();
#pragma unroll
    for (int it = 0; it < 16; ++it) {
        int i = g * E_ + it * 1024 + t;
        int d = __builtin_nontemporal_load(&dst[i]);
        int sv = __builtin_nontemporal_load(&src[i]);
        int p = atomicAdd(&lcnt[d], 1);
        bucket[(size_t)g * EPAD + p] = g * N_ + sv;
    }
}

// ---------------- token stream via MFMA (1 wave); writes P rows into y1/y2 ----------------
__global__ __launch_bounds__(64) void k_tok(const void* __restrict__ tokens,
                                            const void* __restrict__ b1,
                                            const void* __restrict__ b2,
                                            const short8* __restrict__ Bfr,
                                            const short8* __restrict__ Bfr2,
                                            const int* __restrict__ flag,
                                            uint32_t* __restrict__ y1,
                                            uint32_t* __restrict__ y2,
                                            float* __restrict__ tok_sum) {
    __shared__ float nm[T_ * 16];
    __shared__ float ist_s[16], idt_s[16];
    __shared__ float htbuf[T_ * 64];
    __shared__ float h1s[T_ * 64];
    int bf = *flag;
    int l = threadIdx.x;
    int m = l & 15, q = l >> 4;
    int mrow = (m < T_) ? m : (T_ - 1);
    short8 afr[4];
    if (bf) {
        const short8* ar = (const short8*)((const uint16_t*)tokens + mrow * F_);
#pragma unroll
        for (int c = 0; c < 4; ++c) afr[c] = ar[c * 4 + q];
    } else {
        const float* ar = (const float*)tokens + mrow * F_;
#pragma unroll
        for (int c = 0; c < 4; ++c)
#pragma unroll
            for (int j = 0; j < 8; ++j) afr[c][j] = to_bf(ar[c * 32 + q * 8 + j]);
    }
    f32x4 accM = {};
    f32x4 acc1[4] = {};
#pragma unroll
    for (int c = 0; c < 4; ++c) {
        accM = __builtin_amdgcn_mfma_f32_16x16x32_bf16(afr[c], Bfr[(c * 5 + 4) * 64 + l], accM, 0, 0, 0);
#pragma unroll
        for (int nt = 0; nt < 4; ++nt)
            acc1[nt] = __builtin_amdgcn_mfma_f32_16x16x32_bf16(afr[c], Bfr[(c * 5 + nt) * 64 + l], acc1[nt], 0, 0, 0);
    }
    int cnt = 0;
#pragma unroll
    for (int r = 0; r < 4; ++r) {
        int row = q * 4 + r;
        if (row < T_ && m < T_ && accM[r] >= TH_INNER) cnt++;
    }
    cnt += __shfl_xor(cnt, 16);
    cnt += __shfl_xor(cnt, 32);
    float deg = 1.f + (float)cnt;
    float istc = 1.f / sqrtf(deg);
    float idtc = 1.f / deg;
    if (q == 0 && m < T_) { ist_s[m] = istc; idt_s[m] = idtc; }
#pragma unroll
    for (int nt = 0; nt < 4; ++nt)
#pragma unroll
        for (int r = 0; r < 4; ++r) {
            int row = q * 4 + r;
            if (row < T_) htbuf[row * 64 + nt * 16 + m] = acc1[nt][r];
        }
    __syncthreads();
    if (m < T_) {
#pragma unroll
        for (int r = 0; r < 4; ++r) {
            int row = q * 4 + r;
            if (row < T_)
                nm[row * 16 + m] = (accM[r] >= TH_INNER) ? ist_s[row] * istc : 0.f;
        }
    }
    __syncthreads();
    float htc[T_];
#pragma unroll
    for (int s = 0; s < T_; ++s) htc[s] = htbuf[s * 64 + l];
    float b1f = ld1(b1, l, bf);
#pragma unroll
    for (int t = 0; t < T_; ++t) {
        float a = htc[t] * idt_s[t] + b1f;
#pragma unroll
        for (int s = 0; s < T_; ++s) a += nm[t * 16 + s] * htc[s];
        a = (a >= 0.f) ? a : 0.01f * a;
        h1s[t * 64 + l] = a;
        float v = ist_s[t] * htc[t];              // P1 row -> y1[BN+1+t]
        float vh = __shfl(v, l + 1);
        if ((l & 1) == 0) y1[(size_t)(BN + 1 + t) * 32 + (l >> 1)] = pack_bf2(v, vh);
    }
    __syncthreads();
    short8 a2fr[2];
#pragma unroll
    for (int c = 0; c < 2; ++c)
#pragma unroll
        for (int j = 0; j < 8; ++j) a2fr[c][j] = to_bf(h1s[mrow * 64 + c * 32 + q * 8 + j]);
    f32x4 acc2[4] = {};
#pragma unroll
    for (int nt = 0; nt < 4; ++nt)
#pragma unroll
        for (int c = 0; c < 2; ++c)
            acc2[nt] = __builtin_amdgcn_mfma_f32_16x16x32_bf16(a2fr[c], Bfr2[(c * 4 + nt) * 64 + l], acc2[nt], 0, 0, 0);
#pragma unroll
    for (int nt = 0; nt < 4; ++nt)
#pragma unroll
        for (int r = 0; r < 4; ++r) {
            int row = q * 4 + r;
            if (row < T_) htbuf[row * 64 + nt * 16 + m] = acc2[nt][r];
        }
    __syncthreads();
    float b2f = ld1(b2, l, bf);
#pragma unroll
    for (int s = 0; s < T_; ++s) htc[s] = htbuf[s * 64 + l];
    float ts = 0.f;
#pragma unroll
    for (int t = 0; t < T_; ++t) {
        float o = htc[t] * idt_s[t] + b2f;
#pragma unroll
        for (int s = 0; s < T_; ++s) o += nm[t * 16 + s] * htc[s];
        ts += o;
        float v = ist_s[t] * htc[t];              // P2 row -> y2[BN+1+t]
        float vh = __shfl(v, l + 1);
        if ((l & 1) == 0) y2[(size_t)(BN + 1 + t) * 32 + (l >> 1)] = pack_bf2(v, vh);
    }
    tok_sum[l] = ts;
}

// ---------------- node GEMM: y1 + virtual-edge append + cnt2 + inv_s ----------------
__global__ __launch_bounds__(256) void k_node_mfma(const void* __restrict__ x,
                                                   const short8* __restrict__ Bfr,
                                                   const int* __restrict__ cnt,
                                                   const int* __restrict__ offs,
                                                   const int* __restrict__ flag,
                                                   uint32_t* __restrict__ y1,
                                                   float* __restrict__ inv_s,
                                                   int* __restrict__ cnt2,
                                                   int* __restrict__ bucket) {
    int bf = *flag;
    int tid = threadIdx.x;
    int lane = tid & 63, wv = tid >> 6;
    int g = blockIdx.x & 63, c = blockIdx.x >> 6;   // XCD swizzle
    int row0 = g * N_ + c * 64 + wv * 16;
    int m = lane & 15, q = lane >> 4;
    int row = row0 + m;
    short8 afr[4];
    if (bf) {
        const short8* ar = (const short8*)((const uint16_t*)x + (size_t)row * F_);
#pragma unroll
        for (int cc = 0; cc < 4; ++cc) afr[cc] = __builtin_nontemporal_load(&ar[cc * 4 + q]);
    } else {
        const float* ar = (const float*)x + (size_t)row * F_;
#pragma unroll
        for (int cc = 0; cc < 4; ++cc)
#pragma unroll
            for (int j = 0; j < 8; ++j)
                afr[cc][j] = to_bf(__builtin_nontemporal_load(&ar[cc * 32 + q * 8 + j]));
    }
    f32x4 acc[5] = {};
#pragma unroll
    for (int nt = 0; nt < 5; ++nt)
#pragma unroll
        for (int cc = 0; cc < 4; ++cc) {
            short8 bfr = Bfr[(cc * 5 + nt) * 64 + lane];
            acc[nt] = __builtin_amdgcn_mfma_f32_16x16x32_bf16(afr[cc], bfr, acc[nt], 0, 0, 0);
        }
    unsigned long long bal[4];
#pragma unroll
    for (int r = 0; r < 4; ++r) {
        int pred = (m < T_) && (acc[4][r] >= TH_CROSS);
        bal[r] = __ballot(pred);
    }
    float isv[4];
#pragma unroll
    for (int r = 0; r < 4; ++r) {
        int node = row0 + q * 4 + r;
        int mask = (int)((bal[r] >> (q * 16)) & 0x3FF);
        int ec = cnt[node];
        int off = offs[node];
        int pc = __popc((unsigned)mask);
        float deg = 1.f + (float)ec + (float)pc;
        isv[r] = 1.f / sqrtf(deg);
        int base = off + ec;
        if (m < T_ && ((mask >> m) & 1))
            bucket[base + __popc((unsigned)(mask & ((1 << m) - 1)))] = BN + 1 + m;
        if (m == 10) bucket[base + pc] = node;
        if (m == 0) { inv_s[node] = isv[r]; cnt2[node] = ec + pc + 1; }
    }
#pragma unroll
    for (int r = 0; r < 4; ++r) {
        int node = row0 + q * 4 + r;
#pragma unroll
        for (int nt = 0; nt < 4; ++nt) {
            float v = acc[nt][r] * isv[r];
            float vh = __shfl(v, lane + 1);
            if ((m & 1) == 0)
                y1[(size_t)node * 32 + nt * 8 + (m >> 1)] = pack_bf2(v, vh);
        }
    }
}

// ---------------- dwordx2 gather: 4 rows/load, J=8 covers 32 edge-slots ----------------
__device__ __forceinline__ void gather4(const uint32_t* __restrict__ yu,
                                        const int* __restrict__ brow,
                                        int idx_cur, int cnt, int lane,
                                        float& lo0, float& hi0, float& lo1, float& hi1) {
    lo0 = hi0 = lo1 = hi1 = 0.f;
    int r4 = lane >> 4, wp = lane & 15;
    int eb = 0;
    while (true) {
        int cbat = min(cnt - eb, 64);
        for (int half = 0; half < 64; half += 32) {
            if (half >= cbat) break;
            int s[8];
#pragma unroll
            for (int j = 0; j < 8; ++j) {
                int e = half + 4 * j + r4;
                int sv = __shfl(idx_cur, e & 63);
                s[j] = (e < cbat) ? sv : BN;     // BN = zero row
            }
            uint2 u[8];
#pragma unroll
            for (int j = 0; j < 8; ++j)
                u[j] = ((const uint2*)(yu + (size_t)s[j] * 32))[wp];
#pragma unroll
            for (int j = 0; j < 8; ++j) {
                lo0 += bflo(u[j].x); hi0 += bfhi(u[j].x);
                lo1 += bflo(u[j].y); hi1 += bfhi(u[j].y);
            }
        }
        eb += 64;
        if (eb >= cnt) break;
        idx_cur = brow[eb + lane];               // rare (cnt > 64)
    }
    lo0 += __shfl_xor(lo0, 16); hi0 += __shfl_xor(hi0, 16);
    lo1 += __shfl_xor(lo1, 16); hi1 += __shfl_xor(hi1, 16);
    lo0 += __shfl_xor(lo0, 32); hi0 += __shfl_xor(hi0, 32);
    lo1 += __shfl_xor(lo1, 32); hi1 += __shfl_xor(hi1, 32);
}

// ---------------- layer1: 8 nodes/wave gather + epilogue + fused h1@W2 -> y2 ----------------
__global__ __launch_bounds__(256, 8) void k_layer1(const uint32_t* __restrict__ y1,
                                                   const float* __restrict__ inv_s,
                                                   const int* __restrict__ cnt2,
                                                   const int* __restrict__ offs,
                                                   const int* __restrict__ bucket,
                                                   const void* __restrict__ b1,
                                                   const short8* __restrict__ Bfr2,
                                                   const int* __restrict__ flag,
                                                   uint32_t* __restrict__ y2) {
    __shared__ uint32_t h1w[4][9 * 36];          // rows 0..7 = h1 pairs; row 8 = zeros
    int bf = *flag;
    int tid = threadIdx.x;
    int lane = tid & 63, wv = tid >> 6;
    int wp = lane & 15;
    if (lane < 36) h1w[wv][8 * 36 + lane] = 0;   // zero row for A-frag rows 8..15
    int g = blockIdx.x & 63, c = blockIdx.x >> 6;   // c in [0,32)
    int nbase = g * N_ + c * 32 + wv * 8;
    int cntv = cnt2[nbase + (lane & 7)];
    int offv = offs[nbase + (lane & 7)];
    float isv = inv_s[nbase + (lane & 7)];
    float bL0 = ld1(b1, 4 * wp + 0, bf), bH0 = ld1(b1, 4 * wp + 1, bf);
    float bL1 = ld1(b1, 4 * wp + 2, bf), bH1 = ld1(b1, 4 * wp + 3, bf);
    int idx = bucket[__shfl(offv, 0) + lane];    // prefetch node 0
    for (int i = 0; i < 8; ++i) {
        int node = nbase + i;
        int cnt_i = __shfl(cntv, i);
        int off_i = __shfl(offv, i);
        int idx_cur = idx;
        if (i < 7) idx = bucket[__shfl(offv, i + 1) + lane];
        float lo0, hi0, lo1, hi1;
        gather4(y1, bucket + off_i, idx_cur, cnt_i, lane, lo0, hi0, lo1, hi1);
        float is = __shfl(isv, i);
        float h0 = lo0 * is + bL0, h1v = hi0 * is + bH0;
        float h2 = lo1 * is + bL1, h3 = hi1 * is + bH1;
        h0 = (h0 >= 0.f) ? h0 : 0.01f * h0;
        h1v = (h1v >= 0.f) ? h1v : 0.01f * h1v;
        h2 = (h2 >= 0.f) ? h2 : 0.01f * h2;
        h3 = (h3 >= 0.f) ? h3 : 0.01f * h3;
        if (lane < 16) {
            h1w[wv][i * 36 + 2 * wp] = pack_bf2(h0, h1v);
            h1w[wv][i * 36 + 2 * wp + 1] = pack_bf2(h2, h3);
        }
    }
    // fused GEMM on a 16-row tile (rows 8..15 read the zero row)
    int m = lane & 15, q = lane >> 4;
    int mr = (m < 8) ? m : 8;
    short8 afr[2];
#pragma unroll
    for (int cc = 0; cc < 2; ++cc)
        afr[cc] = *(const short8*)&h1w[wv][mr * 36 + cc * 16 + q * 4];
    f32x4 acc[4] = {};
#pragma unroll
    for (int nt = 0; nt < 4; ++nt)
#pragma unroll
        for (int cc = 0; cc < 2; ++cc)
            acc[nt] = __builtin_amdgcn_mfma_f32_16x16x32_bf16(afr[cc], Bfr2[(cc * 4 + nt) * 64 + lane], acc[nt], 0, 0, 0);
#pragma unroll
    for (int r = 0; r < 4; ++r) {
        int tr = q * 4 + r;                      // tile row = node offset
        if (tr < 8) {
            int node = nbase + tr;
            float is = __shfl(isv, tr);
#pragma unroll
            for (int nt = 0; nt < 4; ++nt) {
                float v = acc[nt][r] * is;
                float vh = __shfl(v, lane + 1);
                if ((m & 1) == 0)
                    y2[(size_t)node * 32 + nt * 8 + (m >> 1)] = pack_bf2(v, vh);
            }
        }
    }
}

// ---------------- layer2: pure bucket gather + pooling ----------------
__global__ __launch_bounds__(256, 8) void k_layer2(const uint32_t* __restrict__ y2,
                                                   const float* __restrict__ inv_s,
                                                   const int* __restrict__ cnt2,
                                                   const int* __restrict__ offs,
                                                   const int* __restrict__ bucket,
                                                   const void* __restrict__ b2,
                                                   const int* __restrict__ flag,
                                                   float* __restrict__ graph_sum) {
    int bf = *flag;
    int tid = threadIdx.x;
    int lane = tid & 63, wv = tid >> 6;
    int wp = lane & 15;
    int g = blockIdx.x & 63, c = blockIdx.x >> 6;   // c in [0,32)
    int nbase = g * N_ + c * 32 + wv * 8;
    int cntv = cnt2[nbase + (lane & 7)];
    int offv = offs[nbase + (lane & 7)];
    float isv = inv_s[nbase + (lane & 7)];
    float bL0 = ld1(b2, 4 * wp + 0, bf), bH0 = ld1(b2, 4 * wp + 1, bf);
    float bL1 = ld1(b2, 4 * wp + 2, bf), bH1 = ld1(b2, 4 * wp + 3, bf);
    int idx = bucket[__shfl(offv, 0) + lane];
    float p0 = 0.f, p1 = 0.f, p2 = 0.f, p3 = 0.f;
    for (int i = 0; i < 8; ++i) {
        int cnt_i = __shfl(cntv, i);
        int off_i = __shfl(offv, i);
        int idx_cur = idx;
        if (i < 7) idx = bucket[__shfl(offv, i + 1) + lane];
        float lo0, hi0, lo1, hi1;
        gather4(y2, bucket + off_i, idx_cur, cnt_i, lane, lo0, hi0, lo1, hi1);
        float is = __shfl(isv, i);
        p0 += lo0 * is + bL0;
        p1 += hi0 * is + bH0;
        p2 += lo1 * is + bL1;
        p3 += hi1 * is + bH1;
    }
    if (lane < 16) {
        atomicAdd(&graph_sum[g * H_ + 4 * wp + 0], p0);
        atomicAdd(&graph_sum[g * H_ + 4 * wp + 1], p1);
        atomicAdd(&graph_sum[g * H_ + 4 * wp + 2], p2);
        atomicAdd(&graph_sum[g * H_ + 4 * wp + 3], p3);
    }
}

// ---------------- pooled emb -> answering head -> softmax ----------------
__global__ __launch_bounds__(64) void k_final(const float* __restrict__ graph_sum,
                                              const float* __restrict__ tok_sum,
                                              const void* __restrict__ Wa,
                                              const void* __restrict__ ba,
                                              const int* __restrict__ flag,
                                              void* __restrict__ out) {
    int bf = *flag;
    int b = blockIdx.x, l = threadIdx.x;
    float e = (tok_sum[l] + graph_sum[b * H_ + l]) * (1.0f / 1034.0f);
    float p0 = e * ld1(Wa, l * 2 + 0, bf);
    float p1 = e * ld1(Wa, l * 2 + 1, bf);
#pragma unroll
    for (int d = 32; d >= 1; d >>= 1) {
        p0 += __shfl_xor(p0, d);
        p1 += __shfl_xor(p1, d);
    }
    if (l == 0) {
        float l0 = p0 + ld1(ba, 0, bf);
        float l1 = p1 + ld1(ba, 1, bf);
        float mx = fmaxf(l0, l1);
        float e0 = expf(l0 - mx), e1 = expf(l1 - mx);
        float s = e0 + e1;
        float o0 = e0 / s, o1 = e1 / s;
        if (bf) {
            ((__hip_bfloat16*)out)[b * 2 + 0] = __float2bfloat16(o0);
            ((__hip_bfloat16*)out)[b * 2 + 1] = __float2bfloat16(o1);
        } else {
            ((float*)out)[b * 2 + 0] = o0;
            ((float*)out)[b * 2 + 1] = o1;
        }
    }
}

extern "C" void kernel_launch(void* const* d_in, const int* in_sizes, int n_in,
                              void* d_out, int out_size, void* d_ws, size_t ws_size,
                              hipStream_t stream) {
    (void)in_sizes; (void)n_in; (void)out_size; (void)ws_size;
    const void* x      = d_in[0];
    const void* tokens = d_in[1];
    const void* W1     = d_in[2];
    const void* b1     = d_in[3];
    const void* W2     = d_in[4];
    const void* b2     = d_in[5];
    const void* Wa     = d_in[6];
    const void* ba     = d_in[7];
    const int* esrc = (const int*)d_in[8];
    const int* edst = (const int*)d_in[9];

    char* w = (char*)d_ws;
    auto alloc = [&](size_t bytes) { void* p = (void*)w; w += (bytes + 255) & ~(size_t)255; return p; };
    int*      cnt       = (int*)alloc(BN * 4);
    int*      cnt2      = (int*)alloc(BN * 4);
    int*      offs      = (int*)alloc(BN * 4);
    float*    inv_s     = (float*)alloc(BN * 4);
    int*      bucket    = (int*)alloc((size_t)B_ * EPAD * 4 + 512);    // 7.3 MB dense CSR
    uint32_t* y1        = (uint32_t*)alloc((size_t)(BN + 12) * 32 * 4); // node rows + pad row BN + P rows BN+1..BN+10
    uint32_t* y2        = (uint32_t*)alloc((size_t)(BN + 12) * 32 * 4);
    float*    tok_sum   = (float*)alloc(H_ * 4);
    float*    graph_sum = (float*)alloc(B_ * H_ * 4);
    short8*   Bfr       = (short8*)alloc(4 * 5 * 64 * sizeof(short8));
    short8*   Bfr2      = (short8*)alloc(2 * 4 * 64 * sizeof(short8));
    int*      dflag     = (int*)alloc(256);

    k_bucket   <<<B_ + 2, 1024, 0, stream>>>(esrc, edst, cnt, offs, bucket, graph_sum,
                                             y1 + (size_t)BN * 32, y2 + (size_t)BN * 32,
                                             W1, W2, tokens, dflag, Bfr, Bfr2);
    k_tok      <<<1, 64, 0, stream>>>(tokens, b1, b2, Bfr, Bfr2, dflag, y1, y2, tok_sum);
    k_node_mfma<<<BN / 64, 256, 0, stream>>>(x, Bfr, cnt, offs, dflag, y1, inv_s, cnt2, bucket);
    k_layer1   <<<BN / 32, 256, 0, stream>>>(y1, inv_s, cnt2, offs, bucket, b1, Bfr2, dflag, y2);
    k_layer2   <<<BN / 32, 256, 0, stream>>>(y2, inv_s, cnt2, offs, bucket, b2, dflag, graph_sum);
    k_final    <<<B_, 64, 0, stream>>>(graph_sum, tok_sum, Wa, ba, dflag, d_out);
}

// Round 13
// 198.383 us; speedup vs baseline: 1.0566x; 1.0566x over previous
//
#include <hip/hip_runtime.h>
#include <hip/hip_bf16.h>
#include <stdint.h>

#define B_ 64
#define N_ 1024
#define E_ 16384
#define F_ 128
#define H_ 64
#define T_ 10
#define BN (B_*N_)   // 65536
#define BE (B_*E_)   // 1048576
#define EPAD (E_ + 12 * N_)   // 28672: per-graph compact CSR region (12 slack/node for virtual edges)

// sigmoid(z) >= p  <=>  z >= log(p/(1-p))
#define TH_INNER (-0.84729786f)   // logit(0.3)
#define TH_CROSS (-2.1972246f)    // logit(0.1)

typedef __attribute__((ext_vector_type(8))) short short8;  // bf16x8 MFMA frag
typedef __attribute__((ext_vector_type(4))) float f32x4;   // MFMA acc

__device__ __forceinline__ float ld1(const void* p, int i, int bf) {
    if (bf) {
        uint16_t u = ((const uint16_t*)p)[i];
        return __uint_as_float(((uint32_t)u) << 16);
    }
    return ((const float*)p)[i];
}

__device__ __forceinline__ short to_bf(float x) {
    return (short)__bfloat16_as_ushort(__float2bfloat16(x));
}

__device__ __forceinline__ uint32_t pack_bf2(float lo, float hi) {
    uint32_t l = (uint32_t)__bfloat16_as_ushort(__float2bfloat16(lo));
    uint32_t h = (uint32_t)__bfloat16_as_ushort(__float2bfloat16(hi));
    return l | (h << 16);
}

__device__ __forceinline__ float bflo(uint32_t u) { return __uint_as_float(u << 16); }
__device__ __forceinline__ float bfhi(uint32_t u) { return __uint_as_float(u & 0xffff0000u); }

// ---------------- block-per-graph: count -> LDS scan -> dense CSR scatter ----------------
__global__ __launch_bounds__(1024) void k_bucket(const int* __restrict__ src,
                                                 const int* __restrict__ dst,
                                                 int* __restrict__ cnt,
                                                 int* __restrict__ offs,
                                                 int* __restrict__ bucket,
                                                 float* __restrict__ gsum,
                                                 uint32_t* __restrict__ y1pad,
                                                 uint32_t* __restrict__ y2pad) {
    __shared__ int lcnt[N_];
    __shared__ int lscan[N_];
    int g = blockIdx.x, t = threadIdx.x;
    lcnt[t] = 0;
    if (t < 64) gsum[g * 64 + t] = 0.f;           // zero this graph's pool row
    if (g == 0) {                                 // zero pad rows once
        if (t < 32) y1pad[t] = 0;
        else if (t < 64) y2pad[t - 32] = 0;
    }
    __syncthreads();
#pragma unroll
    for (int it = 0; it < 16; ++it) {
        int i = g * E_ + it * 1024 + t;
        atomicAdd(&lcnt[dst[i]], 1);
    }
    __syncthreads();
    int v = lcnt[t];
    lscan[t] = v;
    __syncthreads();
    for (int d = 1; d < 1024; d <<= 1) {          // inclusive scan
        int u = (t >= d) ? lscan[t - d] : 0;
        __syncthreads();
        lscan[t] += u;
        __syncthreads();
    }
    int base = (lscan[t] - v) + 12 * t;           // exclusive prefix + virtual-edge slack
    cnt[g * N_ + t] = v;
    offs[g * N_ + t] = g * EPAD + base;           // absolute offset into bucket
    __syncthreads();
    lcnt[t] = base;                               // reuse as within-graph cursor
    __syncthreads();
#pragma unroll
    for (int it = 0; it < 16; ++it) {
        int i = g * E_ + it * 1024 + t;
        int d = dst[i];
        int p = atomicAdd(&lcnt[d], 1);
        bucket[(size_t)g * EPAD + p] = g * N_ + src[i];
    }
}

// ---------------- B fragments (W1|tokens^T and W2) + publish dtype flag ----------------
__global__ __launch_bounds__(256) void k_prep(const void* __restrict__ W1,
                                              const void* __restrict__ W2,
                                              const void* __restrict__ tokens,
                                              int* __restrict__ flag,
                                              short8* __restrict__ Bfr,
                                              short8* __restrict__ Bfr2) {
    uint32_t du = ((const uint32_t*)tokens)[threadIdx.x & 63];
    float dlo = __uint_as_float(du << 16);
    unsigned long long vote = __ballot(fabsf(dlo) <= 1.0f);
    int bf = (vote == ~0ull) ? 1 : 0;
    if (blockIdx.x == 0 && threadIdx.x == 0) *flag = bf;

    int f = blockIdx.x * 256 + threadIdx.x;      // [0, 1792)
    if (f < 1280) {                              // Bfr: [128 x 80] = W1 | tokens^T
        int c = f / 320, rem = f % 320;
        int nt = rem / 64, lane = rem % 64;
        int q = lane >> 4, n = nt * 16 + (lane & 15);
        int k0 = c * 32 + q * 8;
        short8 v;
#pragma unroll
        for (int j = 0; j < 8; ++j) {
            int k = k0 + j;
            float x = 0.f;
            if (n < H_) x = ld1(W1, k * H_ + n, bf);
            else if (n < H_ + T_) x = ld1(tokens, (n - H_) * F_ + k, bf);
            v[j] = to_bf(x);
        }
        Bfr[f] = v;
    } else {                                     // Bfr2: W2 [64 x 64]
        int f2 = f - 1280;
        int c = f2 / 256, rem = f2 % 256;
        int nt = rem / 64, lane = rem % 64;
        int q = lane >> 4, n = nt * 16 + (lane & 15);
        int k0 = c * 32 + q * 8;
        short8 v;
#pragma unroll
        for (int j = 0; j < 8; ++j) v[j] = to_bf(ld1(W2, (k0 + j) * H_ + n, bf));
        Bfr2[f2] = v;
    }
}

// ---------------- token stream via MFMA (1 wave); writes P rows into y1/y2 ----------------
__global__ __launch_bounds__(64) void k_tok(const void* __restrict__ tokens,
                                            const void* __restrict__ b1,
                                            const void* __restrict__ b2,
                                            const short8* __restrict__ Bfr,
                                            const short8* __restrict__ Bfr2,
                                            const int* __restrict__ flag,
                                            uint32_t* __restrict__ y1,
                                            uint32_t* __restrict__ y2,
                                            float* __restrict__ tok_sum) {
    __shared__ float nm[T_ * 16];
    __shared__ float ist_s[16], idt_s[16];
    __shared__ float htbuf[T_ * 64];
    __shared__ float h1s[T_ * 64];
    int bf = *flag;
    int l = threadIdx.x;
    int m = l & 15, q = l >> 4;
    int mrow = (m < T_) ? m : (T_ - 1);
    short8 afr[4];
    if (bf) {
        const short8* ar = (const short8*)((const uint16_t*)tokens + mrow * F_);
#pragma unroll
        for (int c = 0; c < 4; ++c) afr[c] = ar[c * 4 + q];
    } else {
        const float* ar = (const float*)tokens + mrow * F_;
#pragma unroll
        for (int c = 0; c < 4; ++c)
#pragma unroll
            for (int j = 0; j < 8; ++j) afr[c][j] = to_bf(ar[c * 32 + q * 8 + j]);
    }
    f32x4 accM = {};
    f32x4 acc1[4] = {};
#pragma unroll
    for (int c = 0; c < 4; ++c) {
        accM = __builtin_amdgcn_mfma_f32_16x16x32_bf16(afr[c], Bfr[(c * 5 + 4) * 64 + l], accM, 0, 0, 0);
#pragma unroll
        for (int nt = 0; nt < 4; ++nt)
            acc1[nt] = __builtin_amdgcn_mfma_f32_16x16x32_bf16(afr[c], Bfr[(c * 5 + nt) * 64 + l], acc1[nt], 0, 0, 0);
    }
    int cnt = 0;
#pragma unroll
    for (int r = 0; r < 4; ++r) {
        int row = q * 4 + r;
        if (row < T_ && m < T_ && accM[r] >= TH_INNER) cnt++;
    }
    cnt += __shfl_xor(cnt, 16);
    cnt += __shfl_xor(cnt, 32);
    float deg = 1.f + (float)cnt;
    float istc = 1.f / sqrtf(deg);
    float idtc = 1.f / deg;
    if (q == 0 && m < T_) { ist_s[m] = istc; idt_s[m] = idtc; }
#pragma unroll
    for (int nt = 0; nt < 4; ++nt)
#pragma unroll
        for (int r = 0; r < 4; ++r) {
            int row = q * 4 + r;
            if (row < T_) htbuf[row * 64 + nt * 16 + m] = acc1[nt][r];
        }
    __syncthreads();
    if (m < T_) {
#pragma unroll
        for (int r = 0; r < 4; ++r) {
            int row = q * 4 + r;
            if (row < T_)
                nm[row * 16 + m] = (accM[r] >= TH_INNER) ? ist_s[row] * istc : 0.f;
        }
    }
    __syncthreads();
    float htc[T_];
#pragma unroll
    for (int s = 0; s < T_; ++s) htc[s] = htbuf[s * 64 + l];
    float b1f = ld1(b1, l, bf);
#pragma unroll
    for (int t = 0; t < T_; ++t) {
        float a = htc[t] * idt_s[t] + b1f;
#pragma unroll
        for (int s = 0; s < T_; ++s) a += nm[t * 16 + s] * htc[s];
        a = (a >= 0.f) ? a : 0.01f * a;
        h1s[t * 64 + l] = a;
        float v = ist_s[t] * htc[t];              // P1 row -> y1[BN+1+t]
        float vh = __shfl(v, l + 1);
        if ((l & 1) == 0) y1[(size_t)(BN + 1 + t) * 32 + (l >> 1)] = pack_bf2(v, vh);
    }
    __syncthreads();
    short8 a2fr[2];
#pragma unroll
    for (int c = 0; c < 2; ++c)
#pragma unroll
        for (int j = 0; j < 8; ++j) a2fr[c][j] = to_bf(h1s[mrow * 64 + c * 32 + q * 8 + j]);
    f32x4 acc2[4] = {};
#pragma unroll
    for (int nt = 0; nt < 4; ++nt)
#pragma unroll
        for (int c = 0; c < 2; ++c)
            acc2[nt] = __builtin_amdgcn_mfma_f32_16x16x32_bf16(a2fr[c], Bfr2[(c * 4 + nt) * 64 + l], acc2[nt], 0, 0, 0);
#pragma unroll
    for (int nt = 0; nt < 4; ++nt)
#pragma unroll
        for (int r = 0; r < 4; ++r) {
            int row = q * 4 + r;
            if (row < T_) htbuf[row * 64 + nt * 16 + m] = acc2[nt][r];
        }
    __syncthreads();
    float b2f = ld1(b2, l, bf);
#pragma unroll
    for (int s = 0; s < T_; ++s) htc[s] = htbuf[s * 64 + l];
    float ts = 0.f;
#pragma unroll
    for (int t = 0; t < T_; ++t) {
        float o = htc[t] * idt_s[t] + b2f;
#pragma unroll
        for (int s = 0; s < T_; ++s) o += nm[t * 16 + s] * htc[s];
        ts += o;
        float v = ist_s[t] * htc[t];              // P2 row -> y2[BN+1+t]
        float vh = __shfl(v, l + 1);
        if ((l & 1) == 0) y2[(size_t)(BN + 1 + t) * 32 + (l >> 1)] = pack_bf2(v, vh);
    }
    tok_sum[l] = ts;
}

// ---------------- node GEMM: y1 + virtual-edge append + cnt2 + inv_s ----------------
__global__ __launch_bounds__(256) void k_node_mfma(const void* __restrict__ x,
                                                   const short8* __restrict__ Bfr,
                                                   const int* __restrict__ cnt,
                                                   const int* __restrict__ offs,
                                                   const int* __restrict__ flag,
                                                   uint32_t* __restrict__ y1,
                                                   float* __restrict__ inv_s,
                                                   int* __restrict__ cnt2,
                                                   int* __restrict__ bucket) {
    int bf = *flag;
    int tid = threadIdx.x;
    int lane = tid & 63, wv = tid >> 6;
    int g = blockIdx.x & 63, c = blockIdx.x >> 6;   // XCD swizzle
    int row0 = g * N_ + c * 64 + wv * 16;
    int m = lane & 15, q = lane >> 4;
    int row = row0 + m;
    short8 afr[4];
    if (bf) {
        const short8* ar = (const short8*)((const uint16_t*)x + (size_t)row * F_);
#pragma unroll
        for (int cc = 0; cc < 4; ++cc) afr[cc] = ar[cc * 4 + q];
    } else {
        const float* ar = (const float*)x + (size_t)row * F_;
#pragma unroll
        for (int cc = 0; cc < 4; ++cc)
#pragma unroll
            for (int j = 0; j < 8; ++j)
                afr[cc][j] = to_bf(ar[cc * 32 + q * 8 + j]);
    }
    f32x4 acc[5] = {};
#pragma unroll
    for (int nt = 0; nt < 5; ++nt)
#pragma unroll
        for (int cc = 0; cc < 4; ++cc) {
            short8 bfr = Bfr[(cc * 5 + nt) * 64 + lane];
            acc[nt] = __builtin_amdgcn_mfma_f32_16x16x32_bf16(afr[cc], bfr, acc[nt], 0, 0, 0);
        }
    unsigned long long bal[4];
#pragma unroll
    for (int r = 0; r < 4; ++r) {
        int pred = (m < T_) && (acc[4][r] >= TH_CROSS);
        bal[r] = __ballot(pred);
    }
    float isv[4];
#pragma unroll
    for (int r = 0; r < 4; ++r) {
        int node = row0 + q * 4 + r;
        int mask = (int)((bal[r] >> (q * 16)) & 0x3FF);
        int ec = cnt[node];
        int off = offs[node];
        int pc = __popc((unsigned)mask);
        float deg = 1.f + (float)ec + (float)pc;
        isv[r] = 1.f / sqrtf(deg);
        int base = off + ec;
        if (m < T_ && ((mask >> m) & 1))
            bucket[base + __popc((unsigned)(mask & ((1 << m) - 1)))] = BN + 1 + m;
        if (m == 10) bucket[base + pc] = node;
        if (m == 0) { inv_s[node] = isv[r]; cnt2[node] = ec + pc + 1; }
    }
#pragma unroll
    for (int r = 0; r < 4; ++r) {
        int node = row0 + q * 4 + r;
#pragma unroll
        for (int nt = 0; nt < 4; ++nt) {
            float v = acc[nt][r] * isv[r];
            float vh = __shfl(v, lane + 1);
            if ((m & 1) == 0)
                y1[(size_t)node * 32 + nt * 8 + (m >> 1)] = pack_bf2(v, vh);
        }
    }
}

// ---------------- dwordx2 gather: 4 rows/load, J=8 covers 32 edge-slots ----------------
__device__ __forceinline__ void gather4(const uint32_t* __restrict__ yu,
                                        const int* __restrict__ brow,
                                        int idx_cur, int cnt, int lane,
                                        float& lo0, float& hi0, float& lo1, float& hi1) {
    lo0 = hi0 = lo1 = hi1 = 0.f;
    int r4 = lane >> 4, wp = lane & 15;
    int eb = 0;
    while (true) {
        int cbat = min(cnt - eb, 64);
        for (int half = 0; half < 64; half += 32) {
            if (half >= cbat) break;
            int s[8];
#pragma unroll
            for (int j = 0; j < 8; ++j) {
                int e = half + 4 * j + r4;
                int sv = __shfl(idx_cur, e & 63);
                s[j] = (e < cbat) ? sv : BN;     // BN = zero row
            }
            uint2 u[8];
#pragma unroll
            for (int j = 0; j < 8; ++j)
                u[j] = ((const uint2*)(yu + (size_t)s[j] * 32))[wp];
#pragma unroll
            for (int j = 0; j < 8; ++j) {
                lo0 += bflo(u[j].x); hi0 += bfhi(u[j].x);
                lo1 += bflo(u[j].y); hi1 += bfhi(u[j].y);
            }
        }
        eb += 64;
        if (eb >= cnt) break;
        idx_cur = brow[eb + lane];               // rare (cnt > 64)
    }
    lo0 += __shfl_xor(lo0, 16); hi0 += __shfl_xor(hi0, 16);
    lo1 += __shfl_xor(lo1, 16); hi1 += __shfl_xor(hi1, 16);
    lo0 += __shfl_xor(lo0, 32); hi0 += __shfl_xor(hi0, 32);
    lo1 += __shfl_xor(lo1, 32); hi1 += __shfl_xor(hi1, 32);
}

// ---------------- layer1: 8 nodes/wave gather + epilogue + fused h1@W2 -> y2 ----------------
__global__ __launch_bounds__(256, 8) void k_layer1(const uint32_t* __restrict__ y1,
                                                   const float* __restrict__ inv_s,
                                                   const int* __restrict__ cnt2,
                                                   const int* __restrict__ offs,
                                                   const int* __restrict__ bucket,
                                                   const void* __restrict__ b1,
                                                   const short8* __restrict__ Bfr2,
                                                   const int* __restrict__ flag,
                                                   uint32_t* __restrict__ y2) {
    __shared__ uint32_t h1w[4][9 * 36];          // rows 0..7 = h1 pairs; row 8 = zeros
    int bf = *flag;
    int tid = threadIdx.x;
    int lane = tid & 63, wv = tid >> 6;
    int wp = lane & 15;
    if (lane < 36) h1w[wv][8 * 36 + lane] = 0;   // zero row for A-frag rows 8..15
    int g = blockIdx.x & 63, c = blockIdx.x >> 6;   // c in [0,32)
    int nbase = g * N_ + c * 32 + wv * 8;
    int cntv = cnt2[nbase + (lane & 7)];
    int offv = offs[nbase + (lane & 7)];
    float isv = inv_s[nbase + (lane & 7)];
    float bL0 = ld1(b1, 4 * wp + 0, bf), bH0 = ld1(b1, 4 * wp + 1, bf);
    float bL1 = ld1(b1, 4 * wp + 2, bf), bH1 = ld1(b1, 4 * wp + 3, bf);
    int idx = bucket[__shfl(offv, 0) + lane];    // prefetch node 0
    for (int i = 0; i < 8; ++i) {
        int node = nbase + i;
        int cnt_i = __shfl(cntv, i);
        int off_i = __shfl(offv, i);
        int idx_cur = idx;
        if (i < 7) idx = bucket[__shfl(offv, i + 1) + lane];
        float lo0, hi0, lo1, hi1;
        gather4(y1, bucket + off_i, idx_cur, cnt_i, lane, lo0, hi0, lo1, hi1);
        float is = __shfl(isv, i);
        float h0 = lo0 * is + bL0, h1v = hi0 * is + bH0;
        float h2 = lo1 * is + bL1, h3 = hi1 * is + bH1;
        h0 = (h0 >= 0.f) ? h0 : 0.01f * h0;
        h1v = (h1v >= 0.f) ? h1v : 0.01f * h1v;
        h2 = (h2 >= 0.f) ? h2 : 0.01f * h2;
        h3 = (h3 >= 0.f) ? h3 : 0.01f * h3;
        if (lane < 16) {
            h1w[wv][i * 36 + 2 * wp] = pack_bf2(h0, h1v);
            h1w[wv][i * 36 + 2 * wp + 1] = pack_bf2(h2, h3);
        }
    }
    // fused GEMM on a 16-row tile (rows 8..15 read the zero row)
    int m = lane & 15, q = lane >> 4;
    int mr = (m < 8) ? m : 8;
    short8 afr[2];
#pragma unroll
    for (int cc = 0; cc < 2; ++cc)
        afr[cc] = *(const short8*)&h1w[wv][mr * 36 + cc * 16 + q * 4];
    f32x4 acc[4] = {};
#pragma unroll
    for (int nt = 0; nt < 4; ++nt)
#pragma unroll
        for (int cc = 0; cc < 2; ++cc)
            acc[nt] = __builtin_amdgcn_mfma_f32_16x16x32_bf16(afr[cc], Bfr2[(cc * 4 + nt) * 64 + lane], acc[nt], 0, 0, 0);
#pragma unroll
    for (int r = 0; r < 4; ++r) {
        int tr = q * 4 + r;                      // tile row = node offset
        if (tr < 8) {
            int node = nbase + tr;
            float is = __shfl(isv, tr);
#pragma unroll
            for (int nt = 0; nt < 4; ++nt) {
                float v = acc[nt][r] * is;
                float vh = __shfl(v, lane + 1);
                if ((m & 1) == 0)
                    y2[(size_t)node * 32 + nt * 8 + (m >> 1)] = pack_bf2(v, vh);
            }
        }
    }
}

// ---------------- layer2: pure bucket gather + pooling ----------------
__global__ __launch_bounds__(256, 8) void k_layer2(const uint32_t* __restrict__ y2,
                                                   const float* __restrict__ inv_s,
                                                   const int* __restrict__ cnt2,
                                                   const int* __restrict__ offs,
                                                   const int* __restrict__ bucket,
                                                   const void* __restrict__ b2,
                                                   const int* __restrict__ flag,
                                                   float* __restrict__ graph_sum) {
    int bf = *flag;
    int tid = threadIdx.x;
    int lane = tid & 63, wv = tid >> 6;
    int wp = lane & 15;
    int g = blockIdx.x & 63, c = blockIdx.x >> 6;   // c in [0,32)
    int nbase = g * N_ + c * 32 + wv * 8;
    int cntv = cnt2[nbase + (lane & 7)];
    int offv = offs[nbase + (lane & 7)];
    float isv = inv_s[nbase + (lane & 7)];
    float bL0 = ld1(b2, 4 * wp + 0, bf), bH0 = ld1(b2, 4 * wp + 1, bf);
    float bL1 = ld1(b2, 4 * wp + 2, bf), bH1 = ld1(b2, 4 * wp + 3, bf);
    int idx = bucket[__shfl(offv, 0) + lane];
    float p0 = 0.f, p1 = 0.f, p2 = 0.f, p3 = 0.f;
    for (int i = 0; i < 8; ++i) {
        int cnt_i = __shfl(cntv, i);
        int off_i = __shfl(offv, i);
        int idx_cur = idx;
        if (i < 7) idx = bucket[__shfl(offv, i + 1) + lane];
        float lo0, hi0, lo1, hi1;
        gather4(y2, bucket + off_i, idx_cur, cnt_i, lane, lo0, hi0, lo1, hi1);
        float is = __shfl(isv, i);
        p0 += lo0 * is + bL0;
        p1 += hi0 * is + bH0;
        p2 += lo1 * is + bL1;
        p3 += hi1 * is + bH1;
    }
    if (lane < 16) {
        atomicAdd(&graph_sum[g * H_ + 4 * wp + 0], p0);
        atomicAdd(&graph_sum[g * H_ + 4 * wp + 1], p1);
        atomicAdd(&graph_sum[g * H_ + 4 * wp + 2], p2);
        atomicAdd(&graph_sum[g * H_ + 4 * wp + 3], p3);
    }
}

// ---------------- pooled emb -> answering head -> softmax ----------------
__global__ __launch_bounds__(64) void k_final(const float* __restrict__ graph_sum,
                                              const float* __restrict__ tok_sum,
                                              const void* __restrict__ Wa,
                                              const void* __restrict__ ba,
                                              const int* __restrict__ flag,
                                              void* __restrict__ out) {
    int bf = *flag;
    int b = blockIdx.x, l = threadIdx.x;
    float e = (tok_sum[l] + graph_sum[b * H_ + l]) * (1.0f / 1034.0f);
    float p0 = e * ld1(Wa, l * 2 + 0, bf);
    float p1 = e * ld1(Wa, l * 2 + 1, bf);
#pragma unroll
    for (int d = 32; d >= 1; d >>= 1) {
        p0 += __shfl_xor(p0, d);
        p1 += __shfl_xor(p1, d);
    }
    if (l == 0) {
        float l0 = p0 + ld1(ba, 0, bf);
        float l1 = p1 + ld1(ba, 1, bf);
        float mx = fmaxf(l0, l1);
        float e0 = expf(l0 - mx), e1 = expf(l1 - mx);
        float s = e0 + e1;
        float o0 = e0 / s, o1 = e1 / s;
        if (bf) {
            ((__hip_bfloat16*)out)[b * 2 + 0] = __float2bfloat16(o0);
            ((__hip_bfloat16*)out)[b * 2 + 1] = __float2bfloat16(o1);
        } else {
            ((float*)out)[b * 2 + 0] = o0;
            ((float*)out)[b * 2 + 1] = o1;
        }
    }
}

extern "C" void kernel_launch(void* const* d_in, const int* in_sizes, int n_in,
                              void* d_out, int out_size, void* d_ws, size_t ws_size,
                              hipStream_t stream) {
    (void)in_sizes; (void)n_in; (void)out_size; (void)ws_size;
    const void* x      = d_in[0];
    const void* tokens = d_in[1];
    const void* W1     = d_in[2];
    const void* b1     = d_in[3];
    const void* W2     = d_in[4];
    const void* b2     = d_in[5];
    const void* Wa     = d_in[6];
    const void* ba     = d_in[7];
    const int* esrc = (const int*)d_in[8];
    const int* edst = (const int*)d_in[9];

    char* w = (char*)d_ws;
    auto alloc = [&](size_t bytes) { void* p = (void*)w; w += (bytes + 255) & ~(size_t)255; return p; };
    int*      cnt       = (int*)alloc(BN * 4);
    int*      cnt2      = (int*)alloc(BN * 4);
    int*      offs      = (int*)alloc(BN * 4);
    float*    inv_s     = (float*)alloc(BN * 4);
    int*      bucket    = (int*)alloc((size_t)B_ * EPAD * 4 + 512);    // 7.3 MB dense CSR
    uint32_t* y1        = (uint32_t*)alloc((size_t)(BN + 12) * 32 * 4); // node rows + pad row BN + P rows BN+1..BN+10
    uint32_t* y2        = (uint32_t*)alloc((size_t)(BN + 12) * 32 * 4);
    float*    tok_sum   = (float*)alloc(H_ * 4);
    float*    graph_sum = (float*)alloc(B_ * H_ * 4);
    short8*   Bfr       = (short8*)alloc(4 * 5 * 64 * sizeof(short8));
    short8*   Bfr2      = (short8*)alloc(2 * 4 * 64 * sizeof(short8));
    int*      dflag     = (int*)alloc(256);

    k_bucket   <<<B_, 1024, 0, stream>>>(esrc, edst, cnt, offs, bucket, graph_sum,
                                         y1 + (size_t)BN * 32, y2 + (size_t)BN * 32);
    k_prep     <<<7, 256, 0, stream>>>(W1, W2, tokens, dflag, Bfr, Bfr2);
    k_tok      <<<1, 64, 0, stream>>>(tokens, b1, b2, Bfr, Bfr2, dflag, y1, y2, tok_sum);
    k_node_mfma<<<BN / 64, 256, 0, stream>>>(x, Bfr, cnt, offs, dflag, y1, inv_s, cnt2, bucket);
    k_layer1   <<<BN / 32, 256, 0, stream>>>(y1, inv_s, cnt2, offs, bucket, b1, Bfr2, dflag, y2);
    k_layer2   <<<BN / 32, 256, 0, stream>>>(y2, inv_s, cnt2, offs, bucket, b2, dflag, graph_sum);
    k_final    <<<B_, 64, 0, stream>>>(graph_sum, tok_sum, Wa, ba, dflag, d_out);
}